// Round 1
// baseline (1655.697 us; speedup 1.0000x reference)
//
#include <hip/hip_runtime.h>
#include <math.h>

#define NB   8
#define SEQ  1024
#define CH   1024
#define DIMS 1024
#define NH   16
#define HD   64
#define MROWS (NB*SEQ)   // 8192

// ---------------------------------------------------------------------------
// SGEMM: C = A(M x 1024) @ W(1024 x 1024) + bias
// SCATTER=1: write C[m][n] to Qh[b][h][p][d] with h=n&15, d=n>>4 (head split)
// SCATTER=0: plain row-major write
// Tile: BM=BN=128, BK=16, 256 threads, 8x8 per thread.
// ---------------------------------------------------------------------------
template<int SCATTER>
__global__ __launch_bounds__(256)
void gemm_kernel(const float* __restrict__ A, const float* __restrict__ W,
                 const float* __restrict__ bias, float* __restrict__ Cout)
{
    const int K = 1024, N = 1024;
    const int BM = 128, BK = 16;

    __shared__ float As[BK][132];   // transposed: As[k][m]
    __shared__ float Bs[BK][132];   // Bs[k][n]

    const int bn = blockIdx.x & 7;    // N/128 = 8
    const int bm = blockIdx.x >> 3;   // M/128 = 64
    const int m0 = bm * BM, n0 = bn * 128;
    const int t  = threadIdx.x;
    const int tx = t & 15, ty = t >> 4;

    float acc[8][8];
    #pragma unroll
    for (int i = 0; i < 8; ++i)
        #pragma unroll
        for (int j = 0; j < 8; ++j) acc[i][j] = 0.f;

    for (int k0 = 0; k0 < K; k0 += BK) {
        // A tile 128x16 -> As[k][m]
        #pragma unroll
        for (int l = 0; l < 2; ++l) {
            int f   = t + l * 256;          // float4 id 0..511
            int row = f >> 2;               // 4 float4 per row
            int kq  = (f & 3) << 2;
            float4 v = *reinterpret_cast<const float4*>(
                &A[(size_t)(m0 + row) * K + k0 + kq]);
            As[kq + 0][row] = v.x; As[kq + 1][row] = v.y;
            As[kq + 2][row] = v.z; As[kq + 3][row] = v.w;
        }
        // B tile 16x128 -> Bs[k][n]
        #pragma unroll
        for (int l = 0; l < 2; ++l) {
            int f  = t + l * 256;
            int kr = f >> 5;                // 32 float4 per row
            int c4 = (f & 31) << 2;
            float4 v = *reinterpret_cast<const float4*>(
                &W[(size_t)(k0 + kr) * N + n0 + c4]);
            *reinterpret_cast<float4*>(&Bs[kr][c4]) = v;
        }
        __syncthreads();

        #pragma unroll
        for (int kk = 0; kk < BK; ++kk) {
            float a[8], b[8];
            #pragma unroll
            for (int i = 0; i < 8; ++i) a[i] = As[kk][ty * 8 + i];
            #pragma unroll
            for (int j = 0; j < 8; ++j) b[j] = Bs[kk][tx * 8 + j];
            #pragma unroll
            for (int i = 0; i < 8; ++i)
                #pragma unroll
                for (int j = 0; j < 8; ++j)
                    acc[i][j] = fmaf(a[i], b[j], acc[i][j]);
        }
        __syncthreads();
    }

    // epilogue
    if (SCATTER) {
        #pragma unroll
        for (int i = 0; i < 8; ++i) {
            int m = m0 + ty * 8 + i;
            int bb = m >> 10, p = m & 1023;
            #pragma unroll
            for (int j = 0; j < 8; ++j) {
                int n = n0 + tx * 8 + j;
                float v = acc[i][j] + bias[n];
                int h = n & 15, d = n >> 4;
                Cout[((size_t)((bb * NH + h) * SEQ + p) << 6) + d] = v;
            }
        }
    } else {
        #pragma unroll
        for (int i = 0; i < 8; ++i) {
            int m = m0 + ty * 8 + i;
            #pragma unroll
            for (int j = 0; j < 8; j += 4) {
                int n = n0 + tx * 8 + j;
                float4 v;
                v.x = acc[i][j + 0] + bias[n + 0];
                v.y = acc[i][j + 1] + bias[n + 1];
                v.z = acc[i][j + 2] + bias[n + 2];
                v.w = acc[i][j + 3] + bias[n + 3];
                *reinterpret_cast<float4*>(&Cout[(size_t)m * 1024 + n]) = v;
            }
        }
    }
}

// ---------------------------------------------------------------------------
// Flash attention, fp32. One block = (b,h) x 32 q-rows. KV tiles of 64.
// Qh/Kh/Vh layout: [b][h][p][64]. heads layout: [b][p][h][64].
// ---------------------------------------------------------------------------
__global__ __launch_bounds__(256)
void attn_kernel(const float* __restrict__ Qh, const float* __restrict__ Kh,
                 const float* __restrict__ Vh, float* __restrict__ heads)
{
    __shared__ float Qs[32][68];    // q rows (pre-scaled by 1/8)
    __shared__ float KsT[64][68];   // transposed K tile: KsT[d][k]
    __shared__ float Vs[64][68];    // V tile row-major
    __shared__ float St[32][66];    // scores then probabilities
    __shared__ float mrow[32], lrow[32], srow[32];

    const int t   = threadIdx.x;
    const int blk = blockIdx.x;
    const int qt  = blk & 31;           // P/32
    const int bh  = blk >> 5;           // b*NH + h
    const size_t base = (size_t)bh * SEQ * HD;
    const int q0 = qt * 32;

    // load Q tile (32x64), fold in 1/sqrt(hd)=1/8
    #pragma unroll
    for (int l = 0; l < 2; ++l) {
        int f = t + l * 256;            // float4 id 0..511
        int r = f >> 4, d4 = (f & 15) << 2;
        float4 v = *reinterpret_cast<const float4*>(
            &Qh[base + (size_t)(q0 + r) * HD + d4]);
        v.x *= 0.125f; v.y *= 0.125f; v.z *= 0.125f; v.w *= 0.125f;
        *reinterpret_cast<float4*>(&Qs[r][d4]) = v;
    }
    if (t < 32) { mrow[t] = -1e30f; lrow[t] = 0.f; }

    float O[4][2];
    #pragma unroll
    for (int r = 0; r < 4; ++r) { O[r][0] = 0.f; O[r][1] = 0.f; }

    const int ig = t >> 5;     // 0..7 : row group (rows ig*4 .. ig*4+3)
    const int lx = t & 31;     // score phase: k2 ; PV phase: d2

    for (int kt = 0; kt < SEQ / 64; ++kt) {
        __syncthreads();   // previous PV done before overwriting tiles
        // load K tile transposed + V tile
        #pragma unroll
        for (int l = 0; l < 4; ++l) {
            int f = t + l * 256;        // float4 id 0..1023
            int r = f >> 4, d4 = (f & 15) << 2;
            float4 kv = *reinterpret_cast<const float4*>(
                &Kh[base + (size_t)(kt * 64 + r) * HD + d4]);
            KsT[d4 + 0][r] = kv.x; KsT[d4 + 1][r] = kv.y;
            KsT[d4 + 2][r] = kv.z; KsT[d4 + 3][r] = kv.w;
            float4 vv = *reinterpret_cast<const float4*>(
                &Vh[base + (size_t)(kt * 64 + r) * HD + d4]);
            *reinterpret_cast<float4*>(&Vs[r][d4]) = vv;
        }
        __syncthreads();

        // scores: St[32][64], thread: rows ig*4+r (r<4), cols {lx, lx+32}
        {
            float s[4][2];
            #pragma unroll
            for (int r = 0; r < 4; ++r) { s[r][0] = 0.f; s[r][1] = 0.f; }
            for (int d = 0; d < HD; ++d) {
                float k0v = KsT[d][lx], k1v = KsT[d][lx + 32];
                #pragma unroll
                for (int r = 0; r < 4; ++r) {
                    float qv = Qs[ig * 4 + r][d];
                    s[r][0] = fmaf(qv, k0v, s[r][0]);
                    s[r][1] = fmaf(qv, k1v, s[r][1]);
                }
            }
            #pragma unroll
            for (int r = 0; r < 4; ++r) {
                St[ig * 4 + r][lx]      = s[r][0];
                St[ig * 4 + r][lx + 32] = s[r][1];
            }
        }
        __syncthreads();

        // online softmax: 8 threads per row
        {
            int i = t >> 3, j = t & 7;
            float mt = -1e30f;
            #pragma unroll
            for (int jj = 0; jj < 8; ++jj) mt = fmaxf(mt, St[i][j + 8 * jj]);
            #pragma unroll
            for (int w = 1; w < 8; w <<= 1) mt = fmaxf(mt, __shfl_xor(mt, w, 64));
            float mold = mrow[i];
            float mnew = fmaxf(mold, mt);
            float lsum = 0.f;
            #pragma unroll
            for (int jj = 0; jj < 8; ++jj) {
                float p = expf(St[i][j + 8 * jj] - mnew);
                St[i][j + 8 * jj] = p;
                lsum += p;
            }
            #pragma unroll
            for (int w = 1; w < 8; w <<= 1) lsum += __shfl_xor(lsum, w, 64);
            if (j == 0) {
                float sc = expf(mold - mnew);
                lrow[i] = lrow[i] * sc + lsum;
                mrow[i] = mnew;
                srow[i] = sc;
            }
        }
        __syncthreads();

        // rescale O, then PV: thread: rows ig*4+r, dims {2*lx, 2*lx+1}
        {
            #pragma unroll
            for (int r = 0; r < 4; ++r) {
                float sc = srow[ig * 4 + r];
                O[r][0] *= sc; O[r][1] *= sc;
            }
            int d = lx * 2;
            for (int k = 0; k < 64; ++k) {
                float v0 = Vs[k][d], v1 = Vs[k][d + 1];
                #pragma unroll
                for (int r = 0; r < 4; ++r) {
                    float p = St[ig * 4 + r][k];
                    O[r][0] = fmaf(p, v0, O[r][0]);
                    O[r][1] = fmaf(p, v1, O[r][1]);
                }
            }
        }
    }

    // finalize: divide by l, write heads[b][q][h][d]
    const int bb = bh >> 4, h = bh & 15;
    const int d = lx * 2;
    #pragma unroll
    for (int r = 0; r < 4; ++r) {
        int i = ig * 4 + r;
        float inv = 1.0f / lrow[i];
        size_t o = ((size_t)(bb * SEQ + q0 + i) * NH + h) * HD + d;
        heads[o]     = O[r][0] * inv;
        heads[o + 1] = O[r][1] * inv;
    }
}

// ---------------------------------------------------------------------------
extern "C" void kernel_launch(void* const* d_in, const int* in_sizes, int n_in,
                              void* d_out, int out_size, void* d_ws, size_t ws_size,
                              hipStream_t stream) {
    const float* q  = (const float*)d_in[0];
    const float* x  = (const float*)d_in[1];
    const float* Wq = (const float*)d_in[2];
    const float* bq = (const float*)d_in[3];
    const float* Wk = (const float*)d_in[4];
    const float* bk = (const float*)d_in[5];
    const float* Wv = (const float*)d_in[6];
    const float* bv = (const float*)d_in[7];
    const float* Wp = (const float*)d_in[8];
    const float* bp = (const float*)d_in[9];
    float* out = (float*)d_out;

    const size_t SZ = (size_t)MROWS * DIMS;   // 8M floats
    float* Qh    = (float*)d_ws;
    float* Kh    = Qh + SZ;
    float* Vh    = Kh + SZ;
    float* heads = Vh + SZ;

    dim3 blk(256);
    dim3 gemm_grid(512);   // (8192/128)*(1024/128)

    hipLaunchKernelGGL((gemm_kernel<1>), gemm_grid, blk, 0, stream, q, Wq, bq, Qh);
    hipLaunchKernelGGL((gemm_kernel<1>), gemm_grid, blk, 0, stream, x, Wk, bk, Kh);
    hipLaunchKernelGGL((gemm_kernel<1>), gemm_grid, blk, 0, stream, x, Wv, bv, Vh);

    dim3 attn_grid(NB * NH * (SEQ / 32));  // 4096
    hipLaunchKernelGGL(attn_kernel, attn_grid, blk, 0, stream, Qh, Kh, Vh, heads);

    hipLaunchKernelGGL((gemm_kernel<0>), gemm_grid, blk, 0, stream, heads, Wp, bp, out);
}

// Round 2
// 970.306 us; speedup vs baseline: 1.7064x; 1.7064x over previous
//
#include <hip/hip_runtime.h>
#include <math.h>

#define NB   8
#define SEQ  1024
#define CH   1024
#define DIMS 1024
#define NH   16
#define HD   64
#define MROWS (NB*SEQ)   // 8192

typedef unsigned short u16;
typedef short short8 __attribute__((ext_vector_type(8)));
typedef float f32x4 __attribute__((ext_vector_type(4)));

__device__ inline u16 f2bf(float f) {
    unsigned u = __float_as_uint(f);
    u += 0x7fff + ((u >> 16) & 1);   // RNE
    return (u16)(u >> 16);
}

#define MFMA16(a, b, c) __builtin_amdgcn_mfma_f32_16x16x32_bf16((a), (b), (c), 0, 0, 0)

// ---------------------------------------------------------------------------
// SGEMM: C = A(M x 1024) @ W(1024 x 1024) + bias
// MODE 0: plain row-major write
// MODE 1: head-split scatter: [b][h][p][d], h=n&15, d=n>>4
// MODE 2: head-split + transpose: [b][h][d][p]  (for V)
// ---------------------------------------------------------------------------
template<int MODE>
__global__ __launch_bounds__(256)
void gemm_kernel(const float* __restrict__ A, const float* __restrict__ W,
                 const float* __restrict__ bias, float* __restrict__ Cout)
{
    const int K = 1024, N = 1024;
    const int BM = 128, BK = 16;

    __shared__ float As[BK][132];   // transposed: As[k][m]
    __shared__ float Bs[BK][132];   // Bs[k][n]

    const int bn = blockIdx.x & 7;
    const int bm = blockIdx.x >> 3;
    const int m0 = bm * BM, n0 = bn * 128;
    const int t  = threadIdx.x;
    const int tx = t & 15, ty = t >> 4;

    float acc[8][8];
    #pragma unroll
    for (int i = 0; i < 8; ++i)
        #pragma unroll
        for (int j = 0; j < 8; ++j) acc[i][j] = 0.f;

    for (int k0 = 0; k0 < K; k0 += BK) {
        #pragma unroll
        for (int l = 0; l < 2; ++l) {
            int f   = t + l * 256;
            int row = f >> 2;
            int kq  = (f & 3) << 2;
            float4 v = *reinterpret_cast<const float4*>(
                &A[(size_t)(m0 + row) * K + k0 + kq]);
            As[kq + 0][row] = v.x; As[kq + 1][row] = v.y;
            As[kq + 2][row] = v.z; As[kq + 3][row] = v.w;
        }
        #pragma unroll
        for (int l = 0; l < 2; ++l) {
            int f  = t + l * 256;
            int kr = f >> 5;
            int c4 = (f & 31) << 2;
            float4 v = *reinterpret_cast<const float4*>(
                &W[(size_t)(k0 + kr) * N + n0 + c4]);
            *reinterpret_cast<float4*>(&Bs[kr][c4]) = v;
        }
        __syncthreads();

        #pragma unroll
        for (int kk = 0; kk < BK; ++kk) {
            float a[8], b[8];
            #pragma unroll
            for (int i = 0; i < 8; ++i) a[i] = As[kk][ty * 8 + i];
            #pragma unroll
            for (int j = 0; j < 8; ++j) b[j] = Bs[kk][tx * 8 + j];
            #pragma unroll
            for (int i = 0; i < 8; ++i)
                #pragma unroll
                for (int j = 0; j < 8; ++j)
                    acc[i][j] = fmaf(a[i], b[j], acc[i][j]);
        }
        __syncthreads();
    }

    if (MODE == 1) {
        #pragma unroll
        for (int i = 0; i < 8; ++i) {
            int m = m0 + ty * 8 + i;
            int bb = m >> 10, p = m & 1023;
            #pragma unroll
            for (int j = 0; j < 8; ++j) {
                int n = n0 + tx * 8 + j;
                float v = acc[i][j] + bias[n];
                int h = n & 15, d = n >> 4;
                Cout[((size_t)((bb * NH + h) * SEQ + p) << 6) + d] = v;
            }
        }
    } else if (MODE == 2) {
        int bb = m0 >> 10, p0 = (m0 & 1023) + ty * 8;
        #pragma unroll
        for (int j = 0; j < 8; ++j) {
            int n = n0 + tx * 8 + j;
            float bv = bias[n];
            int h = n & 15, d = n >> 4;
            size_t base = ((size_t)(bb * NH + h) * HD + d) * SEQ + p0;
            float4 a0, a1;
            a0.x = acc[0][j] + bv; a0.y = acc[1][j] + bv;
            a0.z = acc[2][j] + bv; a0.w = acc[3][j] + bv;
            a1.x = acc[4][j] + bv; a1.y = acc[5][j] + bv;
            a1.z = acc[6][j] + bv; a1.w = acc[7][j] + bv;
            *reinterpret_cast<float4*>(&Cout[base])     = a0;
            *reinterpret_cast<float4*>(&Cout[base + 4]) = a1;
        }
    } else {
        #pragma unroll
        for (int i = 0; i < 8; ++i) {
            int m = m0 + ty * 8 + i;
            #pragma unroll
            for (int j = 0; j < 8; j += 4) {
                int n = n0 + tx * 8 + j;
                float4 v;
                v.x = acc[i][j + 0] + bias[n + 0];
                v.y = acc[i][j + 1] + bias[n + 1];
                v.z = acc[i][j + 2] + bias[n + 2];
                v.w = acc[i][j + 3] + bias[n + 3];
                *reinterpret_cast<float4*>(&Cout[(size_t)m * 1024 + n]) = v;
            }
        }
    }
}

// ---------------------------------------------------------------------------
// MFMA flash attention (bf16 inputs, fp32 accum).
// Block = (b,h) x 64 q-rows; 4 waves x 16 rows. KV tile = 64.
// Qh,Kh: [b][h][p][64] fp32.  Vt: [b][h][64][p] fp32 (d-major).
// heads: [b][p][h][64] fp32.
// ---------------------------------------------------------------------------
__global__ __launch_bounds__(256)
void attn_mfma_kernel(const float* __restrict__ Qh, const float* __restrict__ Kh,
                      const float* __restrict__ Vt, float* __restrict__ heads)
{
    __shared__ u16 Ks[64][72];        // K tile row-major  [kv][d]
    __shared__ u16 Vs[64][72];        // V tile transposed [d][kv]
    __shared__ u16 Ps[4][16][72];     // per-wave P tile   [q][kv]

    const int t  = threadIdx.x;
    const int w  = t >> 6;
    const int l  = t & 63;
    const int lo = l & 15, hi = l >> 4;

    const int qt = blockIdx.x & 15;
    const int bh = blockIdx.x >> 4;           // b*NH + h
    const int q0 = qt * 64;
    const size_t kbase = (size_t)bh * (SEQ * HD);
    const size_t vbase = (size_t)bh * (HD * SEQ);

    union S8 { short8 s; u16 u[8]; };

    // Q A-fragments (held for whole kernel), pre-scaled by 1/sqrt(64)=0.125
    S8 aq[2];
    {
        const int qr = q0 + w * 16 + lo;
        #pragma unroll
        for (int s = 0; s < 2; ++s) {
            const float* p = &Qh[kbase + (size_t)qr * HD + s * 32 + hi * 8];
            float4 v0 = *reinterpret_cast<const float4*>(p);
            float4 v1 = *reinterpret_cast<const float4*>(p + 4);
            aq[s].u[0] = f2bf(v0.x * 0.125f); aq[s].u[1] = f2bf(v0.y * 0.125f);
            aq[s].u[2] = f2bf(v0.z * 0.125f); aq[s].u[3] = f2bf(v0.w * 0.125f);
            aq[s].u[4] = f2bf(v1.x * 0.125f); aq[s].u[5] = f2bf(v1.y * 0.125f);
            aq[s].u[6] = f2bf(v1.z * 0.125f); aq[s].u[7] = f2bf(v1.w * 0.125f);
        }
    }

    f32x4 o[4];
    #pragma unroll
    for (int dg = 0; dg < 4; ++dg) o[dg] = (f32x4){0.f, 0.f, 0.f, 0.f};
    float m_run[4], l_run[4];
    #pragma unroll
    for (int r = 0; r < 4; ++r) { m_run[r] = -1e30f; l_run[r] = 0.f; }

    for (int kt = 0; kt < SEQ / 64; ++kt) {
        const int kv0 = kt * 64;
        __syncthreads();   // prev tile fully consumed
        // stage K (row-major) and V (already transposed in global) as bf16
        #pragma unroll
        for (int it = 0; it < 4; ++it) {
            int f = t + it * 256;
            int r = f >> 4, c4 = (f & 15) << 2;
            float4 kv4 = *reinterpret_cast<const float4*>(
                &Kh[kbase + (size_t)(kv0 + r) * HD + c4]);
            uint2 pk;
            pk.x = (unsigned)f2bf(kv4.x) | ((unsigned)f2bf(kv4.y) << 16);
            pk.y = (unsigned)f2bf(kv4.z) | ((unsigned)f2bf(kv4.w) << 16);
            *reinterpret_cast<uint2*>(&Ks[r][c4]) = pk;
            float4 vv4 = *reinterpret_cast<const float4*>(
                &Vt[vbase + (size_t)r * SEQ + kv0 + c4]);
            uint2 pv;
            pv.x = (unsigned)f2bf(vv4.x) | ((unsigned)f2bf(vv4.y) << 16);
            pv.y = (unsigned)f2bf(vv4.z) | ((unsigned)f2bf(vv4.w) << 16);
            *reinterpret_cast<uint2*>(&Vs[r][c4]) = pv;
        }
        __syncthreads();   // K,V ready

        // scores S = Q K^T / 8  (16x64 per wave)
        f32x4 sc[4];
        #pragma unroll
        for (int cg = 0; cg < 4; ++cg) sc[cg] = (f32x4){0.f, 0.f, 0.f, 0.f};
        #pragma unroll
        for (int s = 0; s < 2; ++s) {
            #pragma unroll
            for (int cg = 0; cg < 4; ++cg) {
                short8 b = *reinterpret_cast<const short8*>(
                    &Ks[cg * 16 + lo][s * 32 + hi * 8]);
                sc[cg] = MFMA16(aq[s].s, b, sc[cg]);
            }
        }

        // online softmax (each wave owns its 16 rows; reduce over lanes 0..15)
        #pragma unroll
        for (int r = 0; r < 4; ++r) {
            float mt = fmaxf(fmaxf(sc[0][r], sc[1][r]), fmaxf(sc[2][r], sc[3][r]));
            mt = fmaxf(mt, __shfl_xor(mt, 1));
            mt = fmaxf(mt, __shfl_xor(mt, 2));
            mt = fmaxf(mt, __shfl_xor(mt, 4));
            mt = fmaxf(mt, __shfl_xor(mt, 8));
            float mnew = fmaxf(m_run[r], mt);
            float corr = __expf(m_run[r] - mnew);
            m_run[r] = mnew;
            float ls = 0.f;
            #pragma unroll
            for (int cg = 0; cg < 4; ++cg) {
                float p = __expf(sc[cg][r] - mnew);
                sc[cg][r] = p;
                ls += p;
            }
            ls += __shfl_xor(ls, 1);
            ls += __shfl_xor(ls, 2);
            ls += __shfl_xor(ls, 4);
            ls += __shfl_xor(ls, 8);
            l_run[r] = l_run[r] * corr + ls;
            #pragma unroll
            for (int dg = 0; dg < 4; ++dg) o[dg][r] *= corr;
            // store P row to LDS (bf16)
            #pragma unroll
            for (int cg = 0; cg < 4; ++cg)
                Ps[w][hi * 4 + r][cg * 16 + lo] = f2bf(sc[cg][r]);
        }
        __syncthreads();   // P visible wave-wide

        // O += P V
        S8 ap[2];
        ap[0].s = *reinterpret_cast<const short8*>(&Ps[w][lo][hi * 8]);
        ap[1].s = *reinterpret_cast<const short8*>(&Ps[w][lo][32 + hi * 8]);
        #pragma unroll
        for (int s = 0; s < 2; ++s) {
            #pragma unroll
            for (int dg = 0; dg < 4; ++dg) {
                short8 b = *reinterpret_cast<const short8*>(
                    &Vs[dg * 16 + lo][s * 32 + hi * 8]);
                o[dg] = MFMA16(ap[s].s, b, o[dg]);
            }
        }
    }

    // finalize: O /= l, write heads[b][p][h][d]
    const int bb = bh >> 4, h = bh & 15;
    #pragma unroll
    for (int r = 0; r < 4; ++r) {
        float inv = 1.0f / l_run[r];
        int qq = q0 + w * 16 + hi * 4 + r;
        size_t ob = ((size_t)(bb * SEQ + qq) * NH + h) * HD + lo;
        #pragma unroll
        for (int dg = 0; dg < 4; ++dg)
            heads[ob + dg * 16] = o[dg][r] * inv;
    }
}

// ---------------------------------------------------------------------------
extern "C" void kernel_launch(void* const* d_in, const int* in_sizes, int n_in,
                              void* d_out, int out_size, void* d_ws, size_t ws_size,
                              hipStream_t stream) {
    const float* q  = (const float*)d_in[0];
    const float* x  = (const float*)d_in[1];
    const float* Wq = (const float*)d_in[2];
    const float* bq = (const float*)d_in[3];
    const float* Wk = (const float*)d_in[4];
    const float* bk = (const float*)d_in[5];
    const float* Wv = (const float*)d_in[6];
    const float* bv = (const float*)d_in[7];
    const float* Wp = (const float*)d_in[8];
    const float* bp = (const float*)d_in[9];
    float* out = (float*)d_out;

    const size_t SZ = (size_t)MROWS * DIMS;
    float* Qh    = (float*)d_ws;
    float* Kh    = Qh + SZ;
    float* Vt    = Kh + SZ;      // [b][h][d][p]
    float* heads = Vt + SZ;

    dim3 blk(256);
    dim3 gemm_grid(512);

    hipLaunchKernelGGL((gemm_kernel<1>), gemm_grid, blk, 0, stream, q, Wq, bq, Qh);
    hipLaunchKernelGGL((gemm_kernel<1>), gemm_grid, blk, 0, stream, x, Wk, bk, Kh);
    hipLaunchKernelGGL((gemm_kernel<2>), gemm_grid, blk, 0, stream, x, Wv, bv, Vt);

    dim3 attn_grid(NB * NH * (SEQ / 64));  // 2048
    hipLaunchKernelGGL(attn_mfma_kernel, attn_grid, blk, 0, stream, Qh, Kh, Vt, heads);

    hipLaunchKernelGGL((gemm_kernel<0>), gemm_grid, blk, 0, stream, heads, Wp, bp, out);
}

// Round 3
// 273.783 us; speedup vs baseline: 6.0475x; 3.5441x over previous
//
#include <hip/hip_runtime.h>
#include <math.h>

#define NB   8
#define SEQ  1024
#define DIMS 1024
#define NH   16
#define HD   64
#define MROWS (NB*SEQ)   // 8192

typedef unsigned short u16;
typedef short short8 __attribute__((ext_vector_type(8)));
typedef float f32x4 __attribute__((ext_vector_type(4)));

__device__ inline u16 f2bf(float f) {
    unsigned u = __float_as_uint(f);
    u += 0x7fff + ((u >> 16) & 1);   // RNE
    return (u16)(u >> 16);
}

#define MFMA16(a, b, c) __builtin_amdgcn_mfma_f32_16x16x32_bf16((a), (b), (c), 0, 0, 0)
#define GLD16(g, l) __builtin_amdgcn_global_load_lds( \
    (const __attribute__((address_space(1))) void*)(g), \
    (__attribute__((address_space(3))) void*)(l), 16, 0, 0)

// ---------------------------------------------------------------------------
// fp32 -> bf16 elementwise (8 elems/thread)
// ---------------------------------------------------------------------------
__global__ __launch_bounds__(256)
void convert_bf16(const float* __restrict__ in, u16* __restrict__ out, int n8)
{
    int i = blockIdx.x * 256 + threadIdx.x;
    if (i >= n8) return;
    float4 v0 = ((const float4*)in)[2 * i];
    float4 v1 = ((const float4*)in)[2 * i + 1];
    union { short8 s; u16 u[8]; } r;
    r.u[0] = f2bf(v0.x); r.u[1] = f2bf(v0.y); r.u[2] = f2bf(v0.z); r.u[3] = f2bf(v0.w);
    r.u[4] = f2bf(v1.x); r.u[5] = f2bf(v1.y); r.u[6] = f2bf(v1.z); r.u[7] = f2bf(v1.w);
    ((short8*)out)[i] = r.s;
}

// ---------------------------------------------------------------------------
// W[k][n] fp32 -> Wt[n][k] bf16 (64x64 tiles, grid 256)
// ---------------------------------------------------------------------------
__global__ __launch_bounds__(256)
void transpose_convert(const float* __restrict__ W, u16* __restrict__ Wt)
{
    __shared__ u16 T[64][72];
    const int t  = threadIdx.x;
    const int k0 = (blockIdx.x >> 4) * 64;
    const int n0 = (blockIdx.x & 15) * 64;
    #pragma unroll
    for (int it = 0; it < 4; ++it) {
        int f  = t + it * 256;            // 0..1023
        int kl = f >> 4;                  // 0..63
        int n4 = (f & 15) * 4;
        float4 v = *(const float4*)&W[(size_t)(k0 + kl) * DIMS + n0 + n4];
        T[n4 + 0][kl] = f2bf(v.x);
        T[n4 + 1][kl] = f2bf(v.y);
        T[n4 + 2][kl] = f2bf(v.z);
        T[n4 + 3][kl] = f2bf(v.w);
    }
    __syncthreads();
    #pragma unroll
    for (int it = 0; it < 2; ++it) {
        int c  = t + it * 256;            // 0..511
        int nl = c >> 3;                  // 0..63
        int k8 = (c & 7) * 8;
        *(short8*)&Wt[(size_t)(n0 + nl) * DIMS + k0 + k8] = *(const short8*)&T[nl][k8];
    }
}

// ---------------------------------------------------------------------------
// bf16 MFMA GEMM: C = A(M x 1024) @ Bt^T + bias.  A:[m][k] bf16, Bt:[n][k] bf16.
// 128x128 tile, BK=64, 4 waves (2x2 of 64x64), global_load_lds staging.
// MODE 0: fp32 row-major to Cout
// MODE 1: bf16, (acc+bias)*scale, scatter [b][h][p][d]  (h=n&15, d=n>>4)
// MODE 2: bf16, scatter-transpose [b][h][d][p]
// ---------------------------------------------------------------------------
template<int MODE>
__global__ __launch_bounds__(256)
void gemm_bf16(const u16* __restrict__ A, const u16* __restrict__ Bt,
               const float* __restrict__ bias, void* __restrict__ Cout, float scale)
{
    __shared__ u16 sm[17408];            // 34.8KB: As(16KB)+Bs(16KB) / epilogue 128x136
    u16* As = sm;                        // [128][64] linear
    u16* Bs = sm + 8192;                 // [128][64] linear

    const int t    = threadIdx.x;
    const int w    = t >> 6, lane = t & 63;
    const int lo   = lane & 15, hi = lane >> 4;
    const int bn   = blockIdx.x & 7;
    const int bm   = blockIdx.x >> 3;
    const int m0   = bm * 128, n0 = bn * 128;
    const int wm   = (w >> 1) * 64, wn = (w & 1) * 64;

    f32x4 acc[4][4];
    #pragma unroll
    for (int mf = 0; mf < 4; ++mf)
        #pragma unroll
        for (int nf = 0; nf < 4; ++nf) acc[mf][nf] = (f32x4){0.f, 0.f, 0.f, 0.f};

    // staging addresses: chunk c = (w*4+i)*64 + lane; row=c>>3, kc=c&7
    const u16* ga[4]; const u16* gb[4]; u16* la[4]; u16* lb[4];
    #pragma unroll
    for (int i = 0; i < 4; ++i) {
        int c   = (w * 4 + i) * 64 + lane;
        int row = c >> 3, kc = c & 7;
        ga[i] = A  + (size_t)(m0 + row) * 1024 + kc * 8;
        gb[i] = Bt + (size_t)(n0 + row) * 1024 + kc * 8;
        la[i] = As + (w * 4 + i) * 512;
        lb[i] = Bs + (w * 4 + i) * 512;
    }

    for (int kt = 0; kt < 16; ++kt) {
        if (kt) __syncthreads();
        #pragma unroll
        for (int i = 0; i < 4; ++i) {
            GLD16(ga[i] + kt * 64, la[i]);
            GLD16(gb[i] + kt * 64, lb[i]);
        }
        __syncthreads();   // compiler drains vmcnt(0) here

        #pragma unroll
        for (int s = 0; s < 2; ++s) {
            short8 fa[4], fb[4];
            #pragma unroll
            for (int mf = 0; mf < 4; ++mf)
                fa[mf] = *(const short8*)&As[(wm + mf * 16 + lo) * 64 + s * 32 + hi * 8];
            #pragma unroll
            for (int nf = 0; nf < 4; ++nf)
                fb[nf] = *(const short8*)&Bs[(wn + nf * 16 + lo) * 64 + s * 32 + hi * 8];
            #pragma unroll
            for (int mf = 0; mf < 4; ++mf)
                #pragma unroll
                for (int nf = 0; nf < 4; ++nf)
                    acc[mf][nf] = MFMA16(fa[mf], fb[nf], acc[mf][nf]);
        }
    }

    if (MODE == 0) {
        float* out = (float*)Cout;
        #pragma unroll
        for (int mf = 0; mf < 4; ++mf)
            #pragma unroll
            for (int j = 0; j < 4; ++j) {
                int r = m0 + wm + mf * 16 + hi * 4 + j;
                #pragma unroll
                for (int nf = 0; nf < 4; ++nf) {
                    int cc = n0 + wn + nf * 16 + lo;
                    out[(size_t)r * 1024 + cc] = acc[mf][nf][j] + bias[cc];
                }
            }
        return;
    }

    __syncthreads();   // staging LDS free for epilogue reuse
    if (MODE == 1) {
        // LDS as L[p=128][h=16][dl=8] stride 136
        #pragma unroll
        for (int mf = 0; mf < 4; ++mf)
            #pragma unroll
            for (int j = 0; j < 4; ++j) {
                int pl = wm + mf * 16 + hi * 4 + j;
                #pragma unroll
                for (int nf = 0; nf < 4; ++nf) {
                    int nl = wn + nf * 16 + lo;
                    int h = nl & 15, dl = nl >> 4;
                    float v = (acc[mf][nf][j] + bias[n0 + nl]) * scale;
                    sm[pl * 136 + h * 8 + dl] = f2bf(v);
                }
            }
        __syncthreads();
        u16* out = (u16*)Cout;
        const int bb = m0 >> 10, p0 = m0 & 1023, dg = n0 >> 4;
        #pragma unroll
        for (int it = 0; it < 8; ++it) {
            int c = t + it * 256;        // 0..2047
            int h = c & 15, pl = c >> 4;
            u16* dst = out + ((size_t)((bb * NH + h) * SEQ + p0 + pl)) * HD + dg;
            *(short8*)dst = *(const short8*)&sm[pl * 136 + h * 8];
        }
    } else {
        // MODE 2: LDS as Lt[n=128][p=128] stride 136
        #pragma unroll
        for (int mf = 0; mf < 4; ++mf)
            #pragma unroll
            for (int j = 0; j < 4; ++j) {
                int pl = wm + mf * 16 + hi * 4 + j;
                #pragma unroll
                for (int nf = 0; nf < 4; ++nf) {
                    int nl = wn + nf * 16 + lo;
                    sm[nl * 136 + pl] = f2bf(acc[mf][nf][j] + bias[n0 + nl]);
                }
            }
        __syncthreads();
        u16* out = (u16*)Cout;
        const int bb = m0 >> 10, p0 = m0 & 1023;
        #pragma unroll
        for (int it = 0; it < 8; ++it) {
            int c  = t + it * 256;       // 0..2047
            int nl = c >> 4, p8 = c & 15;
            int ng = n0 + nl;
            int h = ng & 15, d = ng >> 4;
            u16* dst = out + ((size_t)((bb * NH + h) * HD + d)) * SEQ + p0 + p8 * 8;
            *(short8*)dst = *(const short8*)&sm[nl * 136 + p8 * 8];
        }
    }
}

// ---------------------------------------------------------------------------
// MFMA flash attention, bf16 I/O. Block = (b,h) x 64 q-rows; 4 waves x 16 rows.
// Qh,Kh: [b][h][p][64] bf16 (Q pre-scaled by 0.125). Vt: [b][h][64][p] bf16.
// heads: [b][p][h][64] bf16.
// ---------------------------------------------------------------------------
__global__ __launch_bounds__(256)
void attn_mfma_kernel(const u16* __restrict__ Qh, const u16* __restrict__ Kh,
                      const u16* __restrict__ Vt, u16* __restrict__ heads)
{
    __shared__ u16 Ks[64][72];        // K tile [kv][d]
    __shared__ u16 Vs[64][72];        // V tile [d][kv]
    __shared__ u16 Ps[4][16][72];     // per-wave P [q][kv]

    const int t  = threadIdx.x;
    const int w  = t >> 6;
    const int l  = t & 63;
    const int lo = l & 15, hi = l >> 4;

    const int qt = blockIdx.x & 15;
    const int bh = blockIdx.x >> 4;
    const int q0 = qt * 64;
    const size_t kbase = (size_t)bh * (SEQ * HD);
    const size_t vbase = (size_t)bh * (HD * SEQ);

    // Q A-fragments (already scaled in GEMM epilogue)
    short8 aq[2];
    {
        const int qr = q0 + w * 16 + lo;
        aq[0] = *(const short8*)&Qh[kbase + (size_t)qr * HD + hi * 8];
        aq[1] = *(const short8*)&Qh[kbase + (size_t)qr * HD + 32 + hi * 8];
    }

    f32x4 o[4];
    #pragma unroll
    for (int dg = 0; dg < 4; ++dg) o[dg] = (f32x4){0.f, 0.f, 0.f, 0.f};
    float m_run[4], l_run[4];
    #pragma unroll
    for (int r = 0; r < 4; ++r) { m_run[r] = -1e30f; l_run[r] = 0.f; }

    for (int kt = 0; kt < SEQ / 64; ++kt) {
        const int kv0 = kt * 64;
        __syncthreads();
        #pragma unroll
        for (int it = 0; it < 2; ++it) {
            int c = t + it * 256;         // 0..511
            int r = c >> 3, c8 = (c & 7) * 8;
            *(short8*)&Ks[r][c8] = *(const short8*)&Kh[kbase + (size_t)(kv0 + r) * HD + c8];
            *(short8*)&Vs[r][c8] = *(const short8*)&Vt[vbase + (size_t)r * SEQ + kv0 + c8];
        }
        __syncthreads();

        // S = Q K^T (16x64 per wave)
        f32x4 sc[4];
        #pragma unroll
        for (int cg = 0; cg < 4; ++cg) sc[cg] = (f32x4){0.f, 0.f, 0.f, 0.f};
        #pragma unroll
        for (int s = 0; s < 2; ++s) {
            #pragma unroll
            for (int cg = 0; cg < 4; ++cg) {
                short8 b = *(const short8*)&Ks[cg * 16 + lo][s * 32 + hi * 8];
                sc[cg] = MFMA16(aq[s], b, sc[cg]);
            }
        }

        // online softmax
        #pragma unroll
        for (int r = 0; r < 4; ++r) {
            float mt = fmaxf(fmaxf(sc[0][r], sc[1][r]), fmaxf(sc[2][r], sc[3][r]));
            mt = fmaxf(mt, __shfl_xor(mt, 1));
            mt = fmaxf(mt, __shfl_xor(mt, 2));
            mt = fmaxf(mt, __shfl_xor(mt, 4));
            mt = fmaxf(mt, __shfl_xor(mt, 8));
            float mnew = fmaxf(m_run[r], mt);
            float corr = __expf(m_run[r] - mnew);
            m_run[r] = mnew;
            float ls = 0.f;
            #pragma unroll
            for (int cg = 0; cg < 4; ++cg) {
                float p = __expf(sc[cg][r] - mnew);
                sc[cg][r] = p;
                ls += p;
            }
            ls += __shfl_xor(ls, 1);
            ls += __shfl_xor(ls, 2);
            ls += __shfl_xor(ls, 4);
            ls += __shfl_xor(ls, 8);
            l_run[r] = l_run[r] * corr + ls;
            #pragma unroll
            for (int dg = 0; dg < 4; ++dg) o[dg][r] *= corr;
            #pragma unroll
            for (int cg = 0; cg < 4; ++cg)
                Ps[w][hi * 4 + r][cg * 16 + lo] = f2bf(sc[cg][r]);
        }
        __syncthreads();

        // O += P V
        short8 ap[2];
        ap[0] = *(const short8*)&Ps[w][lo][hi * 8];
        ap[1] = *(const short8*)&Ps[w][lo][32 + hi * 8];
        #pragma unroll
        for (int s = 0; s < 2; ++s) {
            #pragma unroll
            for (int dg = 0; dg < 4; ++dg) {
                short8 b = *(const short8*)&Vs[dg * 16 + lo][s * 32 + hi * 8];
                o[dg] = MFMA16(ap[s], b, o[dg]);
            }
        }
    }

    const int bb = bh >> 4, h = bh & 15;
    #pragma unroll
    for (int r = 0; r < 4; ++r) {
        float inv = 1.0f / l_run[r];
        int qq = q0 + w * 16 + hi * 4 + r;
        size_t ob = ((size_t)(bb * SEQ + qq) * NH + h) * HD + lo;
        #pragma unroll
        for (int dg = 0; dg < 4; ++dg)
            heads[ob + dg * 16] = f2bf(o[dg][r] * inv);
    }
}

// ---------------------------------------------------------------------------
extern "C" void kernel_launch(void* const* d_in, const int* in_sizes, int n_in,
                              void* d_out, int out_size, void* d_ws, size_t ws_size,
                              hipStream_t stream) {
    const float* q  = (const float*)d_in[0];
    const float* x  = (const float*)d_in[1];
    const float* Wq = (const float*)d_in[2];
    const float* bq = (const float*)d_in[3];
    const float* Wk = (const float*)d_in[4];
    const float* bk = (const float*)d_in[5];
    const float* Wv = (const float*)d_in[6];
    const float* bv = (const float*)d_in[7];
    const float* Wp = (const float*)d_in[8];
    const float* bp = (const float*)d_in[9];
    float* out = (float*)d_out;

    const size_t SZ = (size_t)MROWS * DIMS;   // 8M elems
    const size_t WZ = (size_t)DIMS * DIMS;    // 1M elems
    u16* qb  = (u16*)d_ws;
    u16* xb  = qb  + SZ;
    u16* Wqt = xb  + SZ;
    u16* Wkt = Wqt + WZ;
    u16* Wvt = Wkt + WZ;
    u16* Wpt = Wvt + WZ;
    u16* Qm  = Wpt + WZ;
    u16* Km  = Qm  + SZ;
    u16* Vm  = Km  + SZ;
    u16* Hm  = Vm  + SZ;

    dim3 blk(256);
    const int n8 = (int)(SZ / 8);

    hipLaunchKernelGGL(convert_bf16, dim3(n8 / 256), blk, 0, stream, q, qb, n8);
    hipLaunchKernelGGL(convert_bf16, dim3(n8 / 256), blk, 0, stream, x, xb, n8);
    hipLaunchKernelGGL(transpose_convert, dim3(256), blk, 0, stream, Wq, Wqt);
    hipLaunchKernelGGL(transpose_convert, dim3(256), blk, 0, stream, Wk, Wkt);
    hipLaunchKernelGGL(transpose_convert, dim3(256), blk, 0, stream, Wv, Wvt);
    hipLaunchKernelGGL(transpose_convert, dim3(256), blk, 0, stream, Wp, Wpt);

    dim3 gemm_grid(512);
    hipLaunchKernelGGL((gemm_bf16<1>), gemm_grid, blk, 0, stream, qb, Wqt, bq, (void*)Qm, 0.125f);
    hipLaunchKernelGGL((gemm_bf16<1>), gemm_grid, blk, 0, stream, xb, Wkt, bk, (void*)Km, 1.0f);
    hipLaunchKernelGGL((gemm_bf16<2>), gemm_grid, blk, 0, stream, xb, Wvt, bv, (void*)Vm, 1.0f);

    dim3 attn_grid(NB * NH * (SEQ / 64));  // 2048
    hipLaunchKernelGGL(attn_mfma_kernel, attn_grid, blk, 0, stream, Qm, Km, Vm, Hm);

    hipLaunchKernelGGL((gemm_bf16<0>), gemm_grid, blk, 0, stream, Hm, Wpt, bp, (void*)out, 1.0f);
}